// Round 7
// baseline (1439.101 us; speedup 1.0000x reference)
//
#include <hip/hip_runtime.h>

#define T_STEPS 2048
#define BATCH   128
#define HID     100     // LSTM hidden size
#define HP      128     // padded h: [0..99]=h, [100]=1.0 (bias), [101]=x_t, 102..127=0
#define NTH     448     // 7 waves; 8 lanes per unit-PAIR, pairs 0..49 active

#define LOG2E 1.44269504088896340736f

typedef float v2f __attribute__((ext_vector_type(2)));

// DPP quad_perm helpers (VALU pipe, immediate ctrl)
template <int CTRL>
__device__ __forceinline__ float dpp_mov(float v) {
    int y = __builtin_amdgcn_update_dpp(0, __float_as_int(v), CTRL, 0xF, 0xF, true);
    return __int_as_float(y);
}
// lane <-> lane^4 exchange (32-lane-group swizzle, BitMode xor=4: 0x101F)
__device__ __forceinline__ float swz_xor4(float v) {
    int y = __builtin_amdgcn_ds_swizzle(__float_as_int(v), 0x101F);
    return __int_as_float(y);
}
// packed f32 fma -> v_pk_fma_f32 (2 MACs/instr)
static __device__ __forceinline__ v2f pk_fma(v2f a, v2f b, v2f c) {
#if __has_builtin(__builtin_elementwise_fma)
    return __builtin_elementwise_fma(a, b, c);
#else
    v2f r; r.x = fmaf(a.x, b.x, c.x); r.y = fmaf(a.y, b.y, c.y); return r;
#endif
}

__global__ __launch_bounds__(NTH)
__attribute__((amdgpu_waves_per_eu(1, 2)))
void lstm_caviar_kernel(
    const float* __restrict__ x,      // [T, B, 1]
    const float* __restrict__ W_ih,   // [400, 1]
    const float* __restrict__ W_hh,   // [400, 100]
    const float* __restrict__ b_ih,   // [400]
    const float* __restrict__ b_hh,   // [400]
    const float* __restrict__ W1,     // [64, 100]
    const float* __restrict__ b1,     // [64]
    const float* __restrict__ W2,     // [1, 64]
    const float* __restrict__ b2,     // [1]
    float* __restrict__ out)          // [1]
{
    __shared__ __align__(16) float h_buf[2][HP];
    __shared__ float x_lds[T_STEPS];
    __shared__ float red_lds[64];

    const int tid = threadIdx.x;
    const int pr  = tid >> 3;     // unit-pair owned by this 8-lane group (units 2pr, 2pr+1)
    const int s8  = tid & 7;      // k-octant lane
    const int s   = tid & 3;      // gate role within quad
    const bool active = (pr < HID / 2);

    // stage batch-0 inputs (x[t,0,0] = flat[t*BATCH]) into LDS once
    for (int t = tid; t < T_STEPS; t += NTH)
        x_lds[t] = x[t * BATCH];
    if (tid < HP) { h_buf[0][tid] = 0.0f; h_buf[1][tid] = 0.0f; }
    __syncthreads();
    if (tid == 0) {
        h_buf[0][100] = 1.0f;        // virtual element: bias multiplier
        h_buf[1][100] = 1.0f;
        h_buf[0][101] = x_lds[0];    // virtual element: x_t
    }

    // Weights as v2f pairs for v_pk_fma_f32. Lane covers k = 4*s8 + 32*m + d
    // (m=0..3, d=0..3) for 8 dot products (4 gates x 2 units). Virtual columns
    // k=100 (bias b_ih+b_hh) and k=101 (W_ih, x feed) land in lane s8=1's
    // slice and flow through the uniform MAC path. Rows pre-scaled by log2(e)
    // (2x for gate g) so activations use raw exp2:
    //   sigmoid(p) = rcp(1 + exp2(-L*p)),  tanh(p) = 2*rcp(1 + exp2(-2L*p)) - 1
    v2f w2[2][4][8];
    #pragma unroll
    for (int u = 0; u < 2; ++u) {
        #pragma unroll
        for (int g = 0; g < 4; ++g) {
            const int unit = active ? (2 * pr + u) : 0;
            const int r = g * HID + unit;
            const float Lg = (g == 2) ? (2.0f * LOG2E) : LOG2E;
            #pragma unroll
            for (int m = 0; m < 4; ++m) {
                #pragma unroll
                for (int p = 0; p < 2; ++p) {
                    const int k0 = 4 * s8 + 32 * m + 2 * p;
                    float v0 = 0.0f, v1 = 0.0f;
                    if (active) {
                        if (k0 < HID)        v0 = W_hh[r * HID + k0];
                        else if (k0 == 100)  v0 = b_ih[r] + b_hh[r];
                        const int k1 = k0 + 1;
                        if (k1 < HID)        v1 = W_hh[r * HID + k1];
                        else if (k1 == 101)  v1 = W_ih[r];
                    }
                    v2f wp; wp.x = Lg * v0; wp.y = Lg * v1;
                    w2[u][g][2 * m + p] = wp;
                }
            }
        }
    }

    const bool b0   = (s & 1) != 0;
    const bool b1h  = (s & 2) != 0;
    const bool is_g = (s == 2);
    const bool wr   = active && (s8 == 0);
    float cA = 0.0f, cB = 0.0f;
    __syncthreads();

    for (int t = 0; t < T_STEPS; ++t) {
        const float* hb = h_buf[t & 1] + 4 * s8;
        float* hn = h_buf[(t + 1) & 1];

        v2f aA0 = {0.f,0.f}, aA1 = {0.f,0.f}, aA2 = {0.f,0.f}, aA3 = {0.f,0.f};
        v2f aB0 = {0.f,0.f}, aB1 = {0.f,0.f}, aB2 = {0.f,0.f}, aB3 = {0.f,0.f};

        #pragma unroll
        for (int m = 0; m < 4; ++m) {
            const float4 hv = *(const float4*)(hb + 32 * m);
            const v2f hlo = {hv.x, hv.y};
            const v2f hhi = {hv.z, hv.w};
            aA0 = pk_fma(w2[0][0][2*m], hlo, aA0); aA0 = pk_fma(w2[0][0][2*m+1], hhi, aA0);
            aA1 = pk_fma(w2[0][1][2*m], hlo, aA1); aA1 = pk_fma(w2[0][1][2*m+1], hhi, aA1);
            aA2 = pk_fma(w2[0][2][2*m], hlo, aA2); aA2 = pk_fma(w2[0][2][2*m+1], hhi, aA2);
            aA3 = pk_fma(w2[0][3][2*m], hlo, aA3); aA3 = pk_fma(w2[0][3][2*m+1], hhi, aA3);
            aB0 = pk_fma(w2[1][0][2*m], hlo, aB0); aB0 = pk_fma(w2[1][0][2*m+1], hhi, aB0);
            aB1 = pk_fma(w2[1][1][2*m], hlo, aB1); aB1 = pk_fma(w2[1][1][2*m+1], hhi, aB1);
            aB2 = pk_fma(w2[1][2][2*m], hlo, aB2); aB2 = pk_fma(w2[1][2][2*m+1], hhi, aB2);
            aB3 = pk_fma(w2[1][3][2*m], hlo, aB3); aB3 = pk_fma(w2[1][3][2*m+1], hhi, aB3);
        }

        // feed next step's x into the next buffer (inactive lane; pre-barrier)
        if (tid == 400) hn[101] = x_lds[(t + 1) & (T_STEPS - 1)];

        const float fA0 = aA0.x + aA0.y, fA1 = aA1.x + aA1.y;
        const float fA2 = aA2.x + aA2.y, fA3 = aA3.x + aA3.y;
        const float fB0 = aB0.x + aB0.y, fB1 = aB1.x + aB1.y;
        const float fB2 = aB2.x + aB2.y, fB3 = aB3.x + aB3.y;

        // quad-local select-then-butterfly (lane s -> quad sum of gate s),
        // then one xor-4 swizzle stage to merge the two quads' k-halves.
        float p01, p01s, p23, p23s, qq, qqs;

        p01  = b0 ? fA1 : fA0;  p01s = b0 ? fA0 : fA1;
        p23  = b0 ? fA3 : fA2;  p23s = b0 ? fA2 : fA3;
        p01 += dpp_mov<0xB1>(p01s);
        p23 += dpp_mov<0xB1>(p23s);
        qq   = b1h ? p23 : p01; qqs  = b1h ? p01 : p23;
        const float qA = qq + dpp_mov<0x4E>(qqs);

        p01  = b0 ? fB1 : fB0;  p01s = b0 ? fB0 : fB1;
        p23  = b0 ? fB3 : fB2;  p23s = b0 ? fB2 : fB3;
        p01 += dpp_mov<0xB1>(p01s);
        p23 += dpp_mov<0xB1>(p23s);
        qq   = b1h ? p23 : p01; qqs  = b1h ? p01 : p23;
        const float qB = qq + dpp_mov<0x4E>(qqs);

        const float totA = qA + swz_xor4(qA);
        const float totB = qB + swz_xor4(qB);

        // lane s activates gate s for both units (i,f,o: sigmoid; g: tanh)
        const float eA   = __builtin_amdgcn_exp2f(-totA);
        const float rA   = __builtin_amdgcn_rcpf(1.0f + eA);
        const float actA = is_g ? fmaf(2.0f, rA, -1.0f) : rA;
        const float eB   = __builtin_amdgcn_exp2f(-totB);
        const float rB   = __builtin_amdgcn_rcpf(1.0f + eB);
        const float actB = is_g ? fmaf(2.0f, rB, -1.0f) : rB;

        // redistribute activations within each quad (both quads identical now)
        const float igA = dpp_mov<0x00>(actA);
        const float fgA = dpp_mov<0x55>(actA);
        const float ggA = dpp_mov<0xAA>(actA);
        const float ogA = dpp_mov<0xFF>(actA);
        const float igB = dpp_mov<0x00>(actB);
        const float fgB = dpp_mov<0x55>(actB);
        const float ggB = dpp_mov<0xAA>(actB);
        const float ogB = dpp_mov<0xFF>(actB);

        cA = fmaf(fgA, cA, igA * ggA);
        cB = fmaf(fgB, cB, igB * ggB);
        const float e2A = __builtin_amdgcn_exp2f(-2.0f * LOG2E * cA);
        const float thA = fmaf(2.0f, __builtin_amdgcn_rcpf(1.0f + e2A), -1.0f);
        const float e2B = __builtin_amdgcn_exp2f(-2.0f * LOG2E * cB);
        const float thB = fmaf(2.0f, __builtin_amdgcn_rcpf(1.0f + e2B), -1.0f);
        const float hA  = ogA * thA;
        const float hB  = ogB * thB;

        if (wr) {
            float2 hv2; hv2.x = hA; hv2.y = hB;
            *(float2*)(hn + 2 * pr) = hv2;   // adjacent units -> one ds_write_b64
        }
        __syncthreads();
    }

    // head: lin = W1 @ h + b1 (64), out = W2 @ lin + b2 (scalar)
    if (tid < 64) {
        const float* rw = W1 + tid * HID;
        const float* hf = h_buf[0];   // T even -> final h in buf 0
        float a = 0.0f;
        for (int k = 0; k < HID; ++k)
            a = fmaf(rw[k], hf[k], a);
        red_lds[tid] = a + b1[tid];
    }
    __syncthreads();
    if (tid == 0) {
        float a = b2[0];
        for (int k = 0; k < 64; ++k)
            a = fmaf(W2[k], red_lds[k], a);
        out[0] = a;
    }
}

extern "C" void kernel_launch(void* const* d_in, const int* in_sizes, int n_in,
                              void* d_out, int out_size, void* d_ws, size_t ws_size,
                              hipStream_t stream) {
    lstm_caviar_kernel<<<1, NTH, 0, stream>>>(
        (const float*)d_in[0],  // input_seq
        (const float*)d_in[1],  // W_ih
        (const float*)d_in[2],  // W_hh
        (const float*)d_in[3],  // b_ih
        (const float*)d_in[4],  // b_hh
        (const float*)d_in[5],  // W1
        (const float*)d_in[6],  // b1
        (const float*)d_in[7],  // W2
        (const float*)d_in[8],  // b2
        (float*)d_out);
}

// Round 9
// 1392.856 us; speedup vs baseline: 1.0332x; 1.0332x over previous
//
#include <hip/hip_runtime.h>
#include <hip/hip_fp16.h>

#define T_STEPS 2048
#define BATCH   128
#define HID     100     // LSTM hidden size
#define HP      112     // padded hidden length (multiple of 16)
#define NTH     448     // 7 waves of 64

#define LOG2E 1.44269504088896340736f

// DPP quad_perm helpers (VALU pipe, immediate ctrl)
template <int CTRL>
__device__ __forceinline__ float dpp_mov(float v) {
    int y = __builtin_amdgcn_update_dpp(0, __float_as_int(v), CTRL, 0xF, 0xF, true);
    return __int_as_float(y);
}

__global__ __launch_bounds__(NTH)
__attribute__((amdgpu_waves_per_eu(1, 2)))
void lstm_caviar_kernel(
    const float* __restrict__ x,      // [T, B, 1]
    const float* __restrict__ W_ih,   // [400, 1]
    const float* __restrict__ W_hh,   // [400, 100]
    const float* __restrict__ b_ih,   // [400]
    const float* __restrict__ b_hh,   // [400]
    const float* __restrict__ W1,     // [64, 100]
    const float* __restrict__ b1,     // [64]
    const float* __restrict__ W2,     // [1, 64]
    const float* __restrict__ b2,     // [1]
    float* __restrict__ out)          // [1]
{
    __shared__ __align__(16) float h_buf[2][HP];
    __shared__ float x_lds[T_STEPS];
    __shared__ float red_lds[64];

    const int tid = threadIdx.x;
    const int j   = tid >> 2;     // hidden unit owned by this quad
    const int s   = tid & 3;      // k-split / gate-specialization lane
    const bool active = (j < HID);

    // stage batch-0 inputs (x[t,0,0] = flat[t*BATCH]) into LDS once
    for (int t = tid; t < T_STEPS; t += NTH)
        x_lds[t] = x[t * BATCH];
    if (tid < HP) { h_buf[0][tid] = 0.0f; h_buf[1][tid] = 0.0f; }

    // W_hh fragments as f16 PAIRS for v_fma_mix_f32 (f32 acc += f16 w * f32 h).
    // Lane covers k = 16*m + 4*s + d, m=0..6, d=0..3; packed (d0,d1),(d2,d3).
    // 112 weights -> 56 packed VGPRs: halves the loop-carried footprint so the
    // allocator homes them in ARCH VGPRs instead of AGPR-parking (the ~4cyc
    // AGPR-sourced-FMA tax = ~40% of R1's busy cycles; see R1/R3/R5/R7 fit).
    // wi/bias stay fp32 (full precision). Rows pre-scaled by log2(e) (2x for
    // gate g) so activations use raw exp2:
    //   sigmoid(p) = rcp(1 + exp2(-L*p)),  tanh(p) = 2*rcp(1 + exp2(-2L*p)) - 1
    int wpk[4][14];
    float wi4[4], bs4[4];
    #pragma unroll
    for (int g = 0; g < 4; ++g) {
        const int gate = g * HID + (active ? j : 0);
        const float Lg = (g == 2) ? (2.0f * LOG2E) : LOG2E;
        const float* row = W_hh + gate * HID;
        #pragma unroll
        for (int m = 0; m < 7; ++m) {
            #pragma unroll
            for (int p = 0; p < 2; ++p) {
                const int k0 = 16 * m + 4 * s + 2 * p;
                const float w0 = (active && k0     < HID) ? Lg * row[k0]     : 0.0f;
                const float w1 = (active && k0 + 1 < HID) ? Lg * row[k0 + 1] : 0.0f;
                const unsigned short u0 = __half_as_ushort(__float2half_rn(w0));
                const unsigned short u1 = __half_as_ushort(__float2half_rn(w1));
                wpk[g][2 * m + p] = (int)u0 | ((int)u1 << 16);
            }
        }
        wi4[g] = active ? 0.25f * Lg * W_ih[gate] : 0.0f;
        bs4[g] = active ? 0.25f * Lg * (b_ih[gate] + b_hh[gate]) : 0.0f;
    }

    const bool b0   = (s & 1) != 0;
    const bool b1h  = (s & 2) != 0;
    const bool is_g = (s == 2);
    float c = 0.0f;
    __syncthreads();

    // 16 v_fma_mix_f32 per m-block: acc(f32) += f16half(w) * h(f32).
    // op_sel_hi[0]=1 -> src0 is f16; op_sel[0] picks low/high half.
    // g-major interleave: 4 independent chains cover the dep latency.
    #define FMA_MIX_BLOCK(m)                                                         \
    {   const float4 hv = *(const float4*)(hb + 16 * (m) + 4 * s);                   \
        asm("v_fma_mix_f32 %0, %8,  %4, %0 op_sel:[0,0,0] op_sel_hi:[1,0,0]\n\t"     \
            "v_fma_mix_f32 %1, %10, %4, %1 op_sel:[0,0,0] op_sel_hi:[1,0,0]\n\t"     \
            "v_fma_mix_f32 %2, %12, %4, %2 op_sel:[0,0,0] op_sel_hi:[1,0,0]\n\t"     \
            "v_fma_mix_f32 %3, %14, %4, %3 op_sel:[0,0,0] op_sel_hi:[1,0,0]\n\t"     \
            "v_fma_mix_f32 %0, %8,  %5, %0 op_sel:[1,0,0] op_sel_hi:[1,0,0]\n\t"     \
            "v_fma_mix_f32 %1, %10, %5, %1 op_sel:[1,0,0] op_sel_hi:[1,0,0]\n\t"     \
            "v_fma_mix_f32 %2, %12, %5, %2 op_sel:[1,0,0] op_sel_hi:[1,0,0]\n\t"     \
            "v_fma_mix_f32 %3, %14, %5, %3 op_sel:[1,0,0] op_sel_hi:[1,0,0]\n\t"     \
            "v_fma_mix_f32 %0, %9,  %6, %0 op_sel:[0,0,0] op_sel_hi:[1,0,0]\n\t"     \
            "v_fma_mix_f32 %1, %11, %6, %1 op_sel:[0,0,0] op_sel_hi:[1,0,0]\n\t"     \
            "v_fma_mix_f32 %2, %13, %6, %2 op_sel:[0,0,0] op_sel_hi:[1,0,0]\n\t"     \
            "v_fma_mix_f32 %3, %15, %6, %3 op_sel:[0,0,0] op_sel_hi:[1,0,0]\n\t"     \
            "v_fma_mix_f32 %0, %9,  %7, %0 op_sel:[1,0,0] op_sel_hi:[1,0,0]\n\t"     \
            "v_fma_mix_f32 %1, %11, %7, %1 op_sel:[1,0,0] op_sel_hi:[1,0,0]\n\t"     \
            "v_fma_mix_f32 %2, %13, %7, %2 op_sel:[1,0,0] op_sel_hi:[1,0,0]\n\t"     \
            "v_fma_mix_f32 %3, %15, %7, %3 op_sel:[1,0,0] op_sel_hi:[1,0,0]"         \
            : "+v"(acc0), "+v"(acc1), "+v"(acc2), "+v"(acc3)                         \
            : "v"(hv.x), "v"(hv.y), "v"(hv.z), "v"(hv.w),                            \
              "v"(wpk[0][2*(m)]), "v"(wpk[0][2*(m)+1]),                              \
              "v"(wpk[1][2*(m)]), "v"(wpk[1][2*(m)+1]),                              \
              "v"(wpk[2][2*(m)]), "v"(wpk[2][2*(m)+1]),                              \
              "v"(wpk[3][2*(m)]), "v"(wpk[3][2*(m)+1]));                             \
    }

    for (int t = 0; t < T_STEPS; ++t) {
        const float* hb = h_buf[t & 1];
        const float xt = x_lds[t];

        float acc0 = fmaf(wi4[0], xt, bs4[0]);
        float acc1 = fmaf(wi4[1], xt, bs4[1]);
        float acc2 = fmaf(wi4[2], xt, bs4[2]);
        float acc3 = fmaf(wi4[3], xt, bs4[3]);

        FMA_MIX_BLOCK(0)
        FMA_MIX_BLOCK(1)
        FMA_MIX_BLOCK(2)
        FMA_MIX_BLOCK(3)
        FMA_MIX_BLOCK(4)
        FMA_MIX_BLOCK(5)
        FMA_MIX_BLOCK(6)

        // Select-then-butterfly transpose-reduce: lane s ends with the FULL
        // sum of gate s (12 VALU ops).
        float p01  = b0 ? acc1 : acc0;
        float p01s = b0 ? acc0 : acc1;
        float p23  = b0 ? acc3 : acc2;
        float p23s = b0 ? acc2 : acc3;
        p01 += dpp_mov<0xB1>(p01s);
        p23 += dpp_mov<0xB1>(p23s);
        float q  = b1h ? p23 : p01;
        float qs = b1h ? p01 : p23;
        const float tot = q + dpp_mov<0x4E>(qs);

        // lane s activates gate s (i,f,o: sigmoid; g: tanh) — log2e baked in
        const float e   = __builtin_amdgcn_exp2f(-tot);
        const float r   = __builtin_amdgcn_rcpf(1.0f + e);
        const float act = is_g ? fmaf(2.0f, r, -1.0f) : r;

        // redistribute the four activations within the quad (DPP broadcasts)
        const float ig = dpp_mov<0x00>(act);
        const float fg = dpp_mov<0x55>(act);
        const float gg = dpp_mov<0xAA>(act);
        const float og = dpp_mov<0xFF>(act);

        c = fmaf(fg, c, ig * gg);
        const float e2 = __builtin_amdgcn_exp2f(-2.0f * LOG2E * c);
        const float r2 = __builtin_amdgcn_rcpf(1.0f + e2);
        const float h  = og * fmaf(2.0f, r2, -1.0f);

        if (active && s == 0)
            h_buf[(t + 1) & 1][j] = h;
        __syncthreads();
    }
    #undef FMA_MIX_BLOCK

    // head: lin = W1 @ h + b1 (64), out = W2 @ lin + b2 (scalar)
    if (tid < 64) {
        const float* rw = W1 + tid * HID;
        const float* hf = h_buf[0];   // T even -> final h in buf 0
        float a = 0.0f;
        for (int k = 0; k < HID; ++k)
            a = fmaf(rw[k], hf[k], a);
        red_lds[tid] = a + b1[tid];
    }
    __syncthreads();
    if (tid == 0) {
        float a = b2[0];
        for (int k = 0; k < 64; ++k)
            a = fmaf(W2[k], red_lds[k], a);
        out[0] = a;
    }
}

extern "C" void kernel_launch(void* const* d_in, const int* in_sizes, int n_in,
                              void* d_out, int out_size, void* d_ws, size_t ws_size,
                              hipStream_t stream) {
    lstm_caviar_kernel<<<1, NTH, 0, stream>>>(
        (const float*)d_in[0],  // input_seq
        (const float*)d_in[1],  // W_ih
        (const float*)d_in[2],  // W_hh
        (const float*)d_in[3],  // b_ih
        (const float*)d_in[4],  // b_hh
        (const float*)d_in[5],  // W1
        (const float*)d_in[6],  // b1
        (const float*)d_in[7],  // W2
        (const float*)d_in[8],  // b2
        (float*)d_out);
}

// Round 10
// 891.156 us; speedup vs baseline: 1.6149x; 1.5630x over previous
//
#include <hip/hip_runtime.h>
#include <hip/hip_fp16.h>

#define T_STEPS 2048
#define BATCH   128
#define HID     100     // LSTM hidden size
#define KP      128     // padded K: [0..99]=h, [100]=1.0 (bias), [101]=x_t, 102..127=0
#define NTH     512     // 8 waves, 2 per SIMD

#define LOG2E 1.44269504088896340736f

typedef _Float16 half8 __attribute__((ext_vector_type(8)));
typedef float    f32x4 __attribute__((ext_vector_type(4)));

__global__ __launch_bounds__(NTH)
void lstm_caviar_kernel(
    const float* __restrict__ x,      // [T, B, 1]
    const float* __restrict__ W_ih,   // [400, 1]
    const float* __restrict__ W_hh,   // [400, 100]
    const float* __restrict__ b_ih,   // [400]
    const float* __restrict__ b_hh,   // [400]
    const float* __restrict__ W1,     // [64, 100]
    const float* __restrict__ b1,     // [64]
    const float* __restrict__ W2,     // [1, 64]
    const float* __restrict__ b2,     // [1]
    float* __restrict__ out)          // [1]
{
    // h kept as f16 extended vector (double-buffered): one barrier per step.
    __shared__ __align__(16) _Float16 hbuf[2][KP];
    __shared__ float x_lds[T_STEPS];
    __shared__ float red_lds[64];

    const int tid = threadIdx.x;
    const int w   = tid >> 6;         // wave id 0..7
    const int c16 = tid & 15;         // MFMA col within tile (m89: col = lane&15)
    const int l16 = (tid >> 4) & 3;   // k-group within wave (k-octet id)
    const int unit = w * 16 + c16;    // hidden unit owned by this thread (0..127; <100 real)
    const bool uvalid = (unit < HID);
    const bool writer = (l16 == 0) && uvalid;   // one of the 4 redundant copies writes h
    const bool feeder = (tid == 463);           // unit 127 (pad): feeds x_{t+1} into next buf

    // stage batch-0 inputs (x[t,0,0] = flat[t*BATCH]) into LDS once
    for (int t = tid; t < T_STEPS; t += NTH)
        x_lds[t] = x[t * BATCH];
    __syncthreads();
    if (tid < KP) {
        const _Float16 v = (tid == 100) ? (_Float16)1.0f : (_Float16)0.0f;
        hbuf[0][tid] = v;             // h=0; [100]=1.0 (bias mult); [101..]=0
        hbuf[1][tid] = v;
        if (tid == 101) hbuf[0][101] = (_Float16)x_lds[0];
    }

    // Static B fragments: B[k][n] = W_ext[perm(n)][k], perm(col w*64+nt*16+c16)
    // = gate nt of unit w*16+c16. A and B are built with the SAME k-labeling
    // (k = kt*32 + l16*8 + j), so any discrepancy vs the true HW k-mapping
    // cancels in the dot product (A/B layouts are transpose-symmetric).
    // Rows pre-scaled by log2e (2x for gate g~) so activations use raw exp2:
    //   sigmoid(p) = rcp(1+exp2(-p)),  tanh baked as 2*rcp(1+exp2(-p)) - 1.
    // Virtual cols: k=100 -> bias (b_ih+b_hh), k=101 -> W_ih (x feed).
    half8 bfr[4][4];                  // [nt(gate)][kt]
    #pragma unroll
    for (int nt = 0; nt < 4; ++nt) {
        const int r  = nt * HID + (uvalid ? unit : 0);
        const float Lg = (nt == 2) ? (2.0f * LOG2E) : LOG2E;
        #pragma unroll
        for (int kt = 0; kt < 4; ++kt) {
            const int k0 = kt * 32 + l16 * 8;
            half8 f;
            #pragma unroll
            for (int j = 0; j < 8; ++j) {
                const int k = k0 + j;
                float val = 0.0f;
                if (uvalid) {
                    if (k < HID)        val = W_hh[r * HID + k];
                    else if (k == 100)  val = b_ih[r] + b_hh[r];
                    else if (k == 101)  val = W_ih[r];
                }
                f[j] = (_Float16)(Lg * val);
            }
            bfr[nt][kt] = f;
        }
    }

    float c = 0.0f;
    __syncthreads();

    for (int t = 0; t < T_STEPS; ++t) {
        const _Float16* hb = hbuf[t & 1];
        _Float16* hn = hbuf[(t + 1) & 1];

        // A = h broadcast to all 16 rows: fragment value depends only on the
        // k-slot -> identical load for every lane in a k-group (LDS broadcast).
        const half8 a0 = *(const half8*)(hb +  0 + l16 * 8);
        const half8 a1 = *(const half8*)(hb + 32 + l16 * 8);
        const half8 a2 = *(const half8*)(hb + 64 + l16 * 8);
        const half8 a3 = *(const half8*)(hb + 96 + l16 * 8);

        f32x4 ai = {0.f,0.f,0.f,0.f}, af = {0.f,0.f,0.f,0.f};
        f32x4 ag = {0.f,0.f,0.f,0.f}, ao = {0.f,0.f,0.f,0.f};

        // 16 MFMAs: 4 gate-accumulators x 4 chained K-tiles (interleaved so
        // consecutive MFMAs hit independent accumulators).
        ai = __builtin_amdgcn_mfma_f32_16x16x32_f16(a0, bfr[0][0], ai, 0, 0, 0);
        af = __builtin_amdgcn_mfma_f32_16x16x32_f16(a0, bfr[1][0], af, 0, 0, 0);
        ag = __builtin_amdgcn_mfma_f32_16x16x32_f16(a0, bfr[2][0], ag, 0, 0, 0);
        ao = __builtin_amdgcn_mfma_f32_16x16x32_f16(a0, bfr[3][0], ao, 0, 0, 0);
        ai = __builtin_amdgcn_mfma_f32_16x16x32_f16(a1, bfr[0][1], ai, 0, 0, 0);
        af = __builtin_amdgcn_mfma_f32_16x16x32_f16(a1, bfr[1][1], af, 0, 0, 0);
        ag = __builtin_amdgcn_mfma_f32_16x16x32_f16(a1, bfr[2][1], ag, 0, 0, 0);
        ao = __builtin_amdgcn_mfma_f32_16x16x32_f16(a1, bfr[3][1], ao, 0, 0, 0);
        ai = __builtin_amdgcn_mfma_f32_16x16x32_f16(a2, bfr[0][2], ai, 0, 0, 0);
        af = __builtin_amdgcn_mfma_f32_16x16x32_f16(a2, bfr[1][2], af, 0, 0, 0);
        ag = __builtin_amdgcn_mfma_f32_16x16x32_f16(a2, bfr[2][2], ag, 0, 0, 0);
        ao = __builtin_amdgcn_mfma_f32_16x16x32_f16(a2, bfr[3][2], ao, 0, 0, 0);
        ai = __builtin_amdgcn_mfma_f32_16x16x32_f16(a3, bfr[0][3], ai, 0, 0, 0);
        af = __builtin_amdgcn_mfma_f32_16x16x32_f16(a3, bfr[1][3], af, 0, 0, 0);
        ag = __builtin_amdgcn_mfma_f32_16x16x32_f16(a3, bfr[2][3], ag, 0, 0, 0);
        ao = __builtin_amdgcn_mfma_f32_16x16x32_f16(a3, bfr[3][3], ao, 0, 0, 0);

        // All 16 C-rows are identical (A rows identical) -> reg 0 of every
        // lane holds gate[col = lane&15] of its tile. This thread's gates:
        const float gi = ai.x, gf = af.x, gg = ag.x, go = ao.x;

        const float ii = __builtin_amdgcn_rcpf(1.0f + __builtin_amdgcn_exp2f(-gi));
        const float ff = __builtin_amdgcn_rcpf(1.0f + __builtin_amdgcn_exp2f(-gf));
        const float gt = fmaf(2.0f, __builtin_amdgcn_rcpf(1.0f + __builtin_amdgcn_exp2f(-gg)), -1.0f);
        const float oo = __builtin_amdgcn_rcpf(1.0f + __builtin_amdgcn_exp2f(-go));

        c = fmaf(ff, c, ii * gt);
        const float e2 = __builtin_amdgcn_exp2f(-2.0f * LOG2E * c);
        const float th = fmaf(2.0f, __builtin_amdgcn_rcpf(1.0f + e2), -1.0f);
        const float h  = oo * th;

        if (writer) hn[unit] = (_Float16)h;
        if (feeder) hn[101] = (_Float16)x_lds[(t + 1) & (T_STEPS - 1)];
        __syncthreads();
    }

    // head: lin = W1 @ h + b1 (64), out = W2 @ lin + b2 (scalar)
    if (tid < 64) {
        const float* rw = W1 + tid * HID;
        const _Float16* hf = hbuf[0];   // T even -> final h in buf 0
        float a = 0.0f;
        for (int k = 0; k < HID; ++k)
            a = fmaf(rw[k], (float)hf[k], a);
        red_lds[tid] = a + b1[tid];
    }
    __syncthreads();
    if (tid == 0) {
        float a = b2[0];
        for (int k = 0; k < 64; ++k)
            a = fmaf(W2[k], red_lds[k], a);
        out[0] = a;
    }
}

extern "C" void kernel_launch(void* const* d_in, const int* in_sizes, int n_in,
                              void* d_out, int out_size, void* d_ws, size_t ws_size,
                              hipStream_t stream) {
    lstm_caviar_kernel<<<1, NTH, 0, stream>>>(
        (const float*)d_in[0],  // input_seq
        (const float*)d_in[1],  // W_ih
        (const float*)d_in[2],  // W_hh
        (const float*)d_in[3],  // b_ih
        (const float*)d_in[4],  // b_hh
        (const float*)d_in[5],  // W1
        (const float*)d_in[6],  // b1
        (const float*)d_in[7],  // W2
        (const float*)d_in[8],  // b2
        (float*)d_out);
}

// Round 11
// 869.091 us; speedup vs baseline: 1.6559x; 1.0254x over previous
//
#include <hip/hip_runtime.h>
#include <hip/hip_fp16.h>

#define T_STEPS 2048
#define BATCH   128
#define HID     100     // LSTM hidden size
#define KP      128     // padded K: [0..99]=h (fp8), 100..127 = 0
#define NTH     512     // 8 waves, 2 per SIMD

#define LOG2E 1.44269504088896340736f

typedef int   i32x8 __attribute__((ext_vector_type(8)));
typedef float f32x4 __attribute__((ext_vector_type(4)));

__global__ __launch_bounds__(NTH)
void lstm_caviar_kernel(
    const float* __restrict__ x,      // [T, B, 1]
    const float* __restrict__ W_ih,   // [400, 1]
    const float* __restrict__ W_hh,   // [400, 100]
    const float* __restrict__ b_ih,   // [400]
    const float* __restrict__ b_hh,   // [400]
    const float* __restrict__ W1,     // [64, 100]
    const float* __restrict__ b1,     // [64]
    const float* __restrict__ W2,     // [1, 64]
    const float* __restrict__ b2,     // [1]
    float* __restrict__ out)          // [1]
{
    // h as fp8 e4m3 (double-buffered, 128 B each): one barrier per step.
    __shared__ __align__(16) unsigned char hbuf[2][KP];
    __shared__ float hfin[KP];        // f32 h copy (head precision)
    __shared__ float x_lds[T_STEPS];
    __shared__ float red_lds[64];

    const int tid  = threadIdx.x;
    const int w    = tid >> 6;        // wave id 0..7
    const int c16  = tid & 15;        // MFMA col (C/D: col = lane&15, m89)
    const int l16  = (tid >> 4) & 3;  // k-group: lane's 32 A/B bytes = k in [l16*32, l16*32+32)
    const int unit = w * 16 + c16;    // hidden unit owned by this thread
    const bool uvalid = (unit < HID);
    const bool writer = (l16 == 0) && uvalid;

    // stage batch-0 inputs (x[t,0,0] = flat[t*BATCH]) into LDS once
    for (int t = tid; t < T_STEPS; t += NTH)
        x_lds[t] = x[t * BATCH];
    if (tid < KP) { hbuf[0][tid] = 0; hbuf[1][tid] = 0; hfin[tid] = 0.0f; }

    // Static B fragments (fp8 e4m3): gate g of this thread's unit; the lane's
    // 32 bytes cover k = l16*32 + (dword d)*4 + byte. A is built with the SAME
    // k-labeling, so any discrepancy vs the true HW k-mapping is a permutation
    // that cancels in the full K-contraction (validated on HW by R10/f16).
    // Rows pre-scaled by log2e (2x for gate g~) so activations use raw exp2:
    //   sigmoid(p) = rcp(1+exp2(-p)),  tanh(p) = 2*rcp(1+exp2(-p)) - 1.
    // Bias + W_ih*x enter via the f32 C-in operand (full precision).
    i32x8 bfr[4];
    float wig[4], bsg[4];
    #pragma unroll
    for (int g = 0; g < 4; ++g) {
        const int r = g * HID + (uvalid ? unit : 0);
        const float Lg = (g == 2) ? (2.0f * LOG2E) : LOG2E;
        i32x8 f;
        #pragma unroll
        for (int d = 0; d < 8; ++d) {
            const int k0 = l16 * 32 + d * 4;
            float v0 = 0.f, v1 = 0.f, v2 = 0.f, v3 = 0.f;
            if (uvalid) {
                if (k0     < HID) v0 = Lg * W_hh[r * HID + k0];
                if (k0 + 1 < HID) v1 = Lg * W_hh[r * HID + k0 + 1];
                if (k0 + 2 < HID) v2 = Lg * W_hh[r * HID + k0 + 2];
                if (k0 + 3 < HID) v3 = Lg * W_hh[r * HID + k0 + 3];
            }
            int reg = __builtin_amdgcn_cvt_pk_fp8_f32(v0, v1, 0,   false);
            reg     = __builtin_amdgcn_cvt_pk_fp8_f32(v2, v3, reg, true);
            f[d] = reg;
        }
        bfr[g] = f;
        wig[g] = uvalid ? Lg * W_ih[r] : 0.0f;
        bsg[g] = uvalid ? Lg * (b_ih[r] + b_hh[r]) : 0.0f;
    }

    float c = 0.0f;
    __syncthreads();

    for (int t = 0; t < T_STEPS; ++t) {
        const unsigned char* hb = hbuf[t & 1];
        unsigned char* hn = hbuf[(t + 1) & 1];
        const float xt = x_lds[t];

        // A = h broadcast to all 16 rows: lane's fragment depends only on its
        // k-group -> two b128 broadcast reads.
        const int4 alo = *(const int4*)(hb + l16 * 32);
        const int4 ahi = *(const int4*)(hb + l16 * 32 + 16);
        i32x8 av;
        av[0] = alo.x; av[1] = alo.y; av[2] = alo.z; av[3] = alo.w;
        av[4] = ahi.x; av[5] = ahi.y; av[6] = ahi.z; av[7] = ahi.w;

        // C-in = bias + W_ih*x (f32, full precision; all rows identical)
        const float p0 = fmaf(wig[0], xt, bsg[0]);
        const float p1 = fmaf(wig[1], xt, bsg[1]);
        const float p2 = fmaf(wig[2], xt, bsg[2]);
        const float p3 = fmaf(wig[3], xt, bsg[3]);
        f32x4 ai = {p0, p0, p0, p0};
        f32x4 af = {p1, p1, p1, p1};
        f32x4 ag = {p2, p2, p2, p2};
        f32x4 ao = {p3, p3, p3, p3};

        // 4 MFMAs, K=128 each (scales = 1.0: e8m0 0x7F in every byte)
        ai = __builtin_amdgcn_mfma_scale_f32_16x16x128_f8f6f4(
                 av, bfr[0], ai, 0, 0, 0, 0x7F7F7F7F, 0, 0x7F7F7F7F);
        af = __builtin_amdgcn_mfma_scale_f32_16x16x128_f8f6f4(
                 av, bfr[1], af, 0, 0, 0, 0x7F7F7F7F, 0, 0x7F7F7F7F);
        ag = __builtin_amdgcn_mfma_scale_f32_16x16x128_f8f6f4(
                 av, bfr[2], ag, 0, 0, 0, 0x7F7F7F7F, 0, 0x7F7F7F7F);
        ao = __builtin_amdgcn_mfma_scale_f32_16x16x128_f8f6f4(
                 av, bfr[3], ao, 0, 0, 0, 0x7F7F7F7F, 0, 0x7F7F7F7F);

        // All C rows identical (A rows identical) -> take reg 0.
        const float gi = ai[0], gf = af[0], gg = ag[0], go = ao[0];

        const float ii = __builtin_amdgcn_rcpf(1.0f + __builtin_amdgcn_exp2f(-gi));
        const float ff = __builtin_amdgcn_rcpf(1.0f + __builtin_amdgcn_exp2f(-gf));
        const float gt = fmaf(2.0f, __builtin_amdgcn_rcpf(1.0f + __builtin_amdgcn_exp2f(-gg)), -1.0f);
        const float oo = __builtin_amdgcn_rcpf(1.0f + __builtin_amdgcn_exp2f(-go));

        c = fmaf(ff, c, ii * gt);
        const float e2 = __builtin_amdgcn_exp2f(-2.0f * LOG2E * c);
        const float th = fmaf(2.0f, __builtin_amdgcn_rcpf(1.0f + e2), -1.0f);
        const float h  = oo * th;

        if (writer) {
            const int pk = __builtin_amdgcn_cvt_pk_fp8_f32(h, 0.0f, 0, false);
            hn[unit] = (unsigned char)(pk & 0xFF);
            hfin[unit] = h;               // full-precision copy for the head
        }
        __syncthreads();
    }

    // head: lin = W1 @ h + b1 (64), out = W2 @ lin + b2 (scalar) — f32 h
    if (tid < 64) {
        const float* rw = W1 + tid * HID;
        float a = 0.0f;
        for (int k = 0; k < HID; ++k)
            a = fmaf(rw[k], hfin[k], a);
        red_lds[tid] = a + b1[tid];
    }
    __syncthreads();
    if (tid == 0) {
        float a = b2[0];
        for (int k = 0; k < 64; ++k)
            a = fmaf(W2[k], red_lds[k], a);
        out[0] = a;
    }
}

extern "C" void kernel_launch(void* const* d_in, const int* in_sizes, int n_in,
                              void* d_out, int out_size, void* d_ws, size_t ws_size,
                              hipStream_t stream) {
    lstm_caviar_kernel<<<1, NTH, 0, stream>>>(
        (const float*)d_in[0],  // input_seq
        (const float*)d_in[1],  // W_ih
        (const float*)d_in[2],  // W_hh
        (const float*)d_in[3],  // b_ih
        (const float*)d_in[4],  // b_hh
        (const float*)d_in[5],  // W1
        (const float*)d_in[6],  // b1
        (const float*)d_in[7],  // W2
        (const float*)d_in[8],  // b2
        (float*)d_out);
}

// Round 12
// 795.333 us; speedup vs baseline: 1.8094x; 1.0927x over previous
//
#include <hip/hip_runtime.h>
#include <hip/hip_fp16.h>

#define T_STEPS 2048
#define BATCH   128
#define HID     100     // LSTM hidden size
#define KP      128     // padded K: [0..99]=h (fp8), 100..127 = 0
#define NTH     512     // 8 waves, 2 per SIMD

#define LOG2E 1.44269504088896340736f

typedef int   i32x8 __attribute__((ext_vector_type(8)));
typedef float f32x4 __attribute__((ext_vector_type(4)));

__global__ __launch_bounds__(NTH)
void lstm_caviar_kernel(
    const float* __restrict__ x,      // [T, B, 1]
    const float* __restrict__ W_ih,   // [400, 1]
    const float* __restrict__ W_hh,   // [400, 100]
    const float* __restrict__ b_ih,   // [400]
    const float* __restrict__ b_hh,   // [400]
    const float* __restrict__ W1,     // [64, 100]
    const float* __restrict__ b1,     // [64]
    const float* __restrict__ W2,     // [1, 64]
    const float* __restrict__ b2,     // [1]
    float* __restrict__ out)          // [1]
{
    // h as fp8 e4m3 (double-buffered, 128 B each): one barrier per step.
    __shared__ __align__(32) unsigned char hbuf[2][KP];
    __shared__ float hfin[KP];        // f32 h (written once, after the loop)
    __shared__ float x_lds[T_STEPS];
    __shared__ float red_lds[64];

    const int tid  = threadIdx.x;
    const int w    = tid >> 6;        // wave id 0..7
    const int c16  = tid & 15;        // MFMA col (C/D: col = lane&15, m89)
    const int l16  = (tid >> 4) & 3;  // k-group: lane's 32 A/B bytes = k in [l16*32, l16*32+32)
    const int unit = w * 16 + c16;    // hidden unit owned by this thread
    const bool uvalid = (unit < HID);
    const bool writer = (l16 == 0) && uvalid;

    // stage batch-0 inputs (x[t,0,0] = flat[t*BATCH]) into LDS once
    for (int t = tid; t < T_STEPS; t += NTH)
        x_lds[t] = x[t * BATCH];
    if (tid < KP) { hbuf[0][tid] = 0; hbuf[1][tid] = 0; }

    // Static B fragments (fp8 e4m3): gate g of this thread's unit; the lane's
    // 32 bytes cover k = l16*32 + (dword d)*4 + byte. A uses the SAME
    // k-labeling, so any discrepancy vs the true HW k-mapping is a permutation
    // that cancels in the K-contraction (validated on HW by R10/R11 passing).
    // Rows pre-scaled by log2e (2x for gate g~) so activations use raw exp2:
    //   sigmoid(p) = rcp(1+exp2(-p)),  tanh(p) = 2*rcp(1+exp2(-p)) - 1.
    // Bias + W_ih*x enter via the f32 C-in operand (full precision).
    i32x8 bfr[4];
    float wig[4], bsg[4];
    #pragma unroll
    for (int g = 0; g < 4; ++g) {
        const int r = g * HID + (uvalid ? unit : 0);
        const float Lg = (g == 2) ? (2.0f * LOG2E) : LOG2E;
        i32x8 f;
        #pragma unroll
        for (int d = 0; d < 8; ++d) {
            const int k0 = l16 * 32 + d * 4;
            float v0 = 0.f, v1 = 0.f, v2 = 0.f, v3 = 0.f;
            if (uvalid) {
                if (k0     < HID) v0 = Lg * W_hh[r * HID + k0];
                if (k0 + 1 < HID) v1 = Lg * W_hh[r * HID + k0 + 1];
                if (k0 + 2 < HID) v2 = Lg * W_hh[r * HID + k0 + 2];
                if (k0 + 3 < HID) v3 = Lg * W_hh[r * HID + k0 + 3];
            }
            int reg = __builtin_amdgcn_cvt_pk_fp8_f32(v0, v1, 0,   false);
            reg     = __builtin_amdgcn_cvt_pk_fp8_f32(v2, v3, reg, true);
            f[d] = reg;
        }
        bfr[g] = f;
        wig[g] = uvalid ? Lg * W_ih[r] : 0.0f;
        bsg[g] = uvalid ? Lg * (b_ih[r] + b_hh[r]) : 0.0f;
    }

    float c = 0.0f;
    float h = 0.0f;
    const int aoff = l16 * 32;
    __syncthreads();

    // One LSTM step: read fp8 h from hb, write new fp8 h to hn.
    // Static buffers (2x unroll) -> no per-step buffer-select address VALU.
    auto step = [&](const unsigned char* hb, unsigned char* hn, const float xt) {
        // A = h broadcast to all 16 rows: lane's fragment depends only on its
        // k-group -> one 32-B broadcast read (2x ds_read_b128, no repack).
        const i32x8 av = *(const i32x8*)(hb + aoff);

        // C-in = bias + W_ih*x (f32, full precision; all rows identical)
        const float p0 = fmaf(wig[0], xt, bsg[0]);
        const float p1 = fmaf(wig[1], xt, bsg[1]);
        const float p2 = fmaf(wig[2], xt, bsg[2]);
        const float p3 = fmaf(wig[3], xt, bsg[3]);
        f32x4 ai = {p0, p0, p0, p0};
        f32x4 af = {p1, p1, p1, p1};
        f32x4 ag = {p2, p2, p2, p2};
        f32x4 ao = {p3, p3, p3, p3};

        // 4 MFMAs, K=128 each (scales = 1.0: e8m0 0x7F in every byte)
        ai = __builtin_amdgcn_mfma_scale_f32_16x16x128_f8f6f4(
                 av, bfr[0], ai, 0, 0, 0, 0x7F7F7F7F, 0, 0x7F7F7F7F);
        af = __builtin_amdgcn_mfma_scale_f32_16x16x128_f8f6f4(
                 av, bfr[1], af, 0, 0, 0, 0x7F7F7F7F, 0, 0x7F7F7F7F);
        ag = __builtin_amdgcn_mfma_scale_f32_16x16x128_f8f6f4(
                 av, bfr[2], ag, 0, 0, 0, 0x7F7F7F7F, 0, 0x7F7F7F7F);
        ao = __builtin_amdgcn_mfma_scale_f32_16x16x128_f8f6f4(
                 av, bfr[3], ao, 0, 0, 0, 0x7F7F7F7F, 0, 0x7F7F7F7F);

        // All C rows identical (A rows identical) -> take reg 0.
        // Ordered for minimal depth to the ds_write: ii/ff/gt -> c -> th -> h.
        const float ii = __builtin_amdgcn_rcpf(1.0f + __builtin_amdgcn_exp2f(-ai[0]));
        const float ff = __builtin_amdgcn_rcpf(1.0f + __builtin_amdgcn_exp2f(-af[0]));
        const float gt = fmaf(2.0f, __builtin_amdgcn_rcpf(1.0f + __builtin_amdgcn_exp2f(-ag[0])), -1.0f);
        c = fmaf(ff, c, ii * gt);
        const float th = fmaf(2.0f, __builtin_amdgcn_rcpf(1.0f + __builtin_amdgcn_exp2f(-2.0f * LOG2E * c)), -1.0f);
        const float oo = __builtin_amdgcn_rcpf(1.0f + __builtin_amdgcn_exp2f(-ao[0]));
        h = oo * th;

        if (writer) {
            const int pk = __builtin_amdgcn_cvt_pk_fp8_f32(h, 0.0f, 0, false);
            hn[unit] = (unsigned char)(pk & 0xFF);
        }
        __syncthreads();
    };

    for (int t = 0; t < T_STEPS; t += 2) {
        step(hbuf[0], hbuf[1], x_lds[t]);
        step(hbuf[1], hbuf[0], x_lds[t + 1]);
    }

    // final h (f32, full precision) for the head — written once
    if (writer) hfin[unit] = h;
    if (tid >= HID && tid < KP) hfin[tid] = 0.0f;
    __syncthreads();

    // head: lin = W1 @ h + b1 (64), out = W2 @ lin + b2 (scalar) — f32 h
    if (tid < 64) {
        const float* rw = W1 + tid * HID;
        float a = 0.0f;
        for (int k = 0; k < HID; ++k)
            a = fmaf(rw[k], hfin[k], a);
        red_lds[tid] = a + b1[tid];
    }
    __syncthreads();
    if (tid == 0) {
        float a = b2[0];
        for (int k = 0; k < 64; ++k)
            a = fmaf(W2[k], red_lds[k], a);
        out[0] = a;
    }
}

extern "C" void kernel_launch(void* const* d_in, const int* in_sizes, int n_in,
                              void* d_out, int out_size, void* d_ws, size_t ws_size,
                              hipStream_t stream) {
    lstm_caviar_kernel<<<1, NTH, 0, stream>>>(
        (const float*)d_in[0],  // input_seq
        (const float*)d_in[1],  // W_ih
        (const float*)d_in[2],  // W_hh
        (const float*)d_in[3],  // b_ih
        (const float*)d_in[4],  // b_hh
        (const float*)d_in[5],  // W1
        (const float*)d_in[6],  // b1
        (const float*)d_in[7],  // W2
        (const float*)d_in[8],  // b2
        (float*)d_out);
}

// Round 13
// 740.833 us; speedup vs baseline: 1.9425x; 1.0736x over previous
//
#include <hip/hip_runtime.h>
#include <hip/hip_fp16.h>

#define T_STEPS 2048
#define BATCH   128
#define HID     100     // LSTM hidden size
#define KP      128     // padded K: [0..99]=h (fp8), 100..127 = 0
#define NTH     448     // 7 waves (units 0..111; wave 8 was pure padding)

#define LOG2E 1.44269504088896340736f

typedef int   i32x8 __attribute__((ext_vector_type(8)));
typedef float f32x4 __attribute__((ext_vector_type(4)));

__global__ __launch_bounds__(NTH)
void lstm_caviar_kernel(
    const float* __restrict__ x,      // [T, B, 1]
    const float* __restrict__ W_ih,   // [400, 1]
    const float* __restrict__ W_hh,   // [400, 100]
    const float* __restrict__ b_ih,   // [400]
    const float* __restrict__ b_hh,   // [400]
    const float* __restrict__ W1,     // [64, 100]
    const float* __restrict__ b1,     // [64]
    const float* __restrict__ W2,     // [1, 64]
    const float* __restrict__ b2,     // [1]
    float* __restrict__ out)          // [1]
{
    // h as fp8 e4m3 (double-buffered, 128 B each): one barrier per step.
    __shared__ __align__(32) unsigned char hbuf[2][KP];
    __shared__ float hfin[KP];        // f32 h (written once, after the loop)
    __shared__ float x_lds[T_STEPS];
    __shared__ float red_lds[64];

    const int tid  = threadIdx.x;
    const int w    = tid >> 6;        // wave id 0..6
    const int c16  = tid & 15;        // MFMA col (C/D: col = lane&15, m89)
    const int l16  = (tid >> 4) & 3;  // k-group: lane's 32 A/B bytes = k in [l16*32, l16*32+32)
    const int unit = w * 16 + c16;    // hidden unit owned by this thread (0..111)
    const bool uvalid = (unit < HID);
    const bool writer = (l16 == 0) && uvalid;

    // stage batch-0 inputs (x[t,0,0] = flat[t*BATCH]) into LDS once
    for (int t = tid; t < T_STEPS; t += NTH)
        x_lds[t] = x[t * BATCH];
    if (tid < KP) { hbuf[0][tid] = 0; hbuf[1][tid] = 0; }

    // Static B fragments (fp8 e4m3): gate g of this thread's unit; the lane's
    // 32 bytes cover k = l16*32 + (dword d)*4 + byte. A uses the SAME
    // k-labeling, so any discrepancy vs the true HW k-mapping is a permutation
    // that cancels in the K-contraction (validated on HW by R10/R11 passing).
    // Rows pre-scaled by log2e (2x for gate g~) so activations use raw exp2:
    //   sigmoid(p) = rcp(1+exp2(-p)),  tanh(p) = 2*rcp(1+exp2(-p)) - 1.
    // Bias + W_ih*x enter as NEGATED scalars (np = -(Lg*(wi*x+b))) merged in
    // the activation via one v_sub: exp2(-tot) = exp2(np - raw). C-in of the
    // MFMA is a persistent ZERO vector (dest != src), killing the per-step
    // {p,p,p,p} splat movs (~16 VALU/thread/step in R12).
    i32x8 bfr[4];
    float nwig[4], nbsg[4];
    #pragma unroll
    for (int g = 0; g < 4; ++g) {
        const int r = g * HID + (uvalid ? unit : 0);
        const float Lg = (g == 2) ? (2.0f * LOG2E) : LOG2E;
        i32x8 f;
        #pragma unroll
        for (int d = 0; d < 8; ++d) {
            const int k0 = l16 * 32 + d * 4;
            float v0 = 0.f, v1 = 0.f, v2 = 0.f, v3 = 0.f;
            if (uvalid) {
                if (k0     < HID) v0 = Lg * W_hh[r * HID + k0];
                if (k0 + 1 < HID) v1 = Lg * W_hh[r * HID + k0 + 1];
                if (k0 + 2 < HID) v2 = Lg * W_hh[r * HID + k0 + 2];
                if (k0 + 3 < HID) v3 = Lg * W_hh[r * HID + k0 + 3];
            }
            int reg = __builtin_amdgcn_cvt_pk_fp8_f32(v0, v1, 0,   false);
            reg     = __builtin_amdgcn_cvt_pk_fp8_f32(v2, v3, reg, true);
            f[d] = reg;
        }
        bfr[g] = f;
        nwig[g] = uvalid ? -Lg * W_ih[r] : 0.0f;
        nbsg[g] = uvalid ? -Lg * (b_ih[r] + b_hh[r]) : 0.0f;
    }

    float c = 0.0f;
    float h = 0.0f;
    const int aoff = l16 * 32;
    const f32x4 czero = {0.f, 0.f, 0.f, 0.f};
    __syncthreads();

    // One LSTM step: read fp8 h from hb, write new fp8 h to hn.
    // Static buffers (2x unroll) -> no per-step buffer-select address VALU.
    auto step = [&](const unsigned char* hb, unsigned char* hn, const float xt) {
        // np_g = -(bias + W_ih*x) (f32, full precision), computed before the
        // A-read so it's off the LDS critical path.
        const float np0 = fmaf(nwig[0], xt, nbsg[0]);
        const float np1 = fmaf(nwig[1], xt, nbsg[1]);
        const float np2 = fmaf(nwig[2], xt, nbsg[2]);
        const float np3 = fmaf(nwig[3], xt, nbsg[3]);

        // A = h broadcast to all 16 rows: lane's fragment depends only on its
        // k-group -> one 32-B broadcast read (2x ds_read_b128, no repack).
        const i32x8 av = *(const i32x8*)(hb + aoff);

        // 4 MFMAs, K=128 each, C-in = persistent zero (scales = 1.0: e8m0 0x7F)
        const f32x4 ai = __builtin_amdgcn_mfma_scale_f32_16x16x128_f8f6f4(
                 av, bfr[0], czero, 0, 0, 0, 0x7F7F7F7F, 0, 0x7F7F7F7F);
        const f32x4 af = __builtin_amdgcn_mfma_scale_f32_16x16x128_f8f6f4(
                 av, bfr[1], czero, 0, 0, 0, 0x7F7F7F7F, 0, 0x7F7F7F7F);
        const f32x4 ag = __builtin_amdgcn_mfma_scale_f32_16x16x128_f8f6f4(
                 av, bfr[2], czero, 0, 0, 0, 0x7F7F7F7F, 0, 0x7F7F7F7F);
        const f32x4 ao = __builtin_amdgcn_mfma_scale_f32_16x16x128_f8f6f4(
                 av, bfr[3], czero, 0, 0, 0, 0x7F7F7F7F, 0, 0x7F7F7F7F);

        // All C rows identical (A rows identical) -> take reg 0.
        // -tot = np - raw (one v_sub each); ordered for minimal write depth.
        const float ii = __builtin_amdgcn_rcpf(1.0f + __builtin_amdgcn_exp2f(np0 - ai[0]));
        const float ff = __builtin_amdgcn_rcpf(1.0f + __builtin_amdgcn_exp2f(np1 - af[0]));
        const float gt = fmaf(2.0f, __builtin_amdgcn_rcpf(1.0f + __builtin_amdgcn_exp2f(np2 - ag[0])), -1.0f);
        c = fmaf(ff, c, ii * gt);
        const float th = fmaf(2.0f, __builtin_amdgcn_rcpf(1.0f + __builtin_amdgcn_exp2f(-2.0f * LOG2E * c)), -1.0f);
        const float oo = __builtin_amdgcn_rcpf(1.0f + __builtin_amdgcn_exp2f(np3 - ao[0]));
        h = oo * th;

        if (writer) {
            const int pk = __builtin_amdgcn_cvt_pk_fp8_f32(h, 0.0f, 0, false);
            hn[unit] = (unsigned char)(pk & 0xFF);
        }
        __syncthreads();
    };

    for (int t = 0; t < T_STEPS; t += 2) {
        step(hbuf[0], hbuf[1], x_lds[t]);
        step(hbuf[1], hbuf[0], x_lds[t + 1]);
    }

    // final h (f32, full precision) for the head — written once
    if (writer) hfin[unit] = h;
    if (tid >= HID && tid < KP) hfin[tid] = 0.0f;
    __syncthreads();

    // head: lin = W1 @ h + b1 (64), out = W2 @ lin + b2 (scalar) — f32 h
    if (tid < 64) {
        const float* rw = W1 + tid * HID;
        float a = 0.0f;
        for (int k = 0; k < HID; ++k)
            a = fmaf(rw[k], hfin[k], a);
        red_lds[tid] = a + b1[tid];
    }
    __syncthreads();
    if (tid == 0) {
        float a = b2[0];
        for (int k = 0; k < 64; ++k)
            a = fmaf(W2[k], red_lds[k], a);
        out[0] = a;
    }
}

extern "C" void kernel_launch(void* const* d_in, const int* in_sizes, int n_in,
                              void* d_out, int out_size, void* d_ws, size_t ws_size,
                              hipStream_t stream) {
    lstm_caviar_kernel<<<1, NTH, 0, stream>>>(
        (const float*)d_in[0],  // input_seq
        (const float*)d_in[1],  // W_ih
        (const float*)d_in[2],  // W_hh
        (const float*)d_in[3],  // b_ih
        (const float*)d_in[4],  // b_hh
        (const float*)d_in[5],  // W1
        (const float*)d_in[6],  // b1
        (const float*)d_in[7],  // W2
        (const float*)d_in[8],  // b2
        (float*)d_out);
}

// Round 14
// 672.436 us; speedup vs baseline: 2.1401x; 1.1017x over previous
//
#include <hip/hip_runtime.h>
#include <hip/hip_fp16.h>

#define T_STEPS 2048
#define BATCH   128
#define HID     100     // LSTM hidden size
#define KP      128     // padded K: [0..99]=h (fp8), 100..127 = 0
#define NTH     448     // 7 waves (units 0..111)

#define LOG2E 1.44269504088896340736f

typedef int   i32x8 __attribute__((ext_vector_type(8)));
typedef float f32x4 __attribute__((ext_vector_type(4)));

// DPP quad_perm helpers (VALU pipe, immediate ctrl)
template <int CTRL>
__device__ __forceinline__ float dpp_mov(float v) {
    int y = __builtin_amdgcn_update_dpp(0, __float_as_int(v), CTRL, 0xF, 0xF, true);
    return __int_as_float(y);
}

__global__ __launch_bounds__(NTH)
void lstm_caviar_kernel(
    const float* __restrict__ x,      // [T, B, 1]
    const float* __restrict__ W_ih,   // [400, 1]
    const float* __restrict__ W_hh,   // [400, 100]
    const float* __restrict__ b_ih,   // [400]
    const float* __restrict__ b_hh,   // [400]
    const float* __restrict__ W1,     // [64, 100]
    const float* __restrict__ b1,     // [64]
    const float* __restrict__ W2,     // [1, 64]
    const float* __restrict__ b2,     // [1]
    float* __restrict__ out)          // [1]
{
    // h as fp8 e4m3 (double-buffered, 128 B each): one barrier per step.
    __shared__ __align__(32) unsigned char hbuf[2][KP];
    __shared__ float hfin[KP];        // f32 h (written once, after the loop)
    __shared__ float x_lds[T_STEPS];
    __shared__ float red_lds[64];

    const int tid  = threadIdx.x;
    const int w    = tid >> 6;        // wave id 0..6
    const int n    = tid & 15;        // MFMA col (C/D: col = lane&15, m89)
    const int gate = n & 3;           // this lane's gate (0=i,1=f,2=g~,3=o)
    const int usub = n >> 2;          // unit-sub within a 4-unit column group
    const int l16  = (tid >> 4) & 3;  // k-group for A/B fragments AND this
                                      // lane's column-group q for activation
    // Column remap: MFMA q's col n = gate (n&3) of unit w*16 + q*4 + (n>>2).
    // => quad (lanes 4u..4u+3) of group q holds all 4 gates of ONE unit ->
    // gate exchange is free quad DPP; each lane does ONE activation (its gate)
    // for the unit below, killing the 4x-redundant transcendental work (R13:
    // 10 trans/thread -> 4).
    const int unit = w * 16 + l16 * 4 + usub;   // unit whose c this lane carries
    const bool uvalid = (unit < HID);
    const bool writer = (gate == 0) && uvalid;
    const bool is_g   = (gate == 2);

    // stage batch-0 inputs (x[t,0,0] = flat[t*BATCH]) into LDS once
    for (int t = tid; t < T_STEPS; t += NTH)
        x_lds[t] = x[t * BATCH];
    if (tid < KP) { hbuf[0][tid] = 0; hbuf[1][tid] = 0; }

    // Static B fragments (fp8 e4m3), one per column-group q. Lane's 32 bytes
    // cover k = l16*32 + d*4 + byte — SAME k-labeling as A, so any mismatch vs
    // the true HW k-mapping cancels in the K-contraction (HW-validated R10+).
    // Rows pre-scaled by log2e (2x for gate g~) so activations use raw exp2.
    // Bias + W_ih*x enter as a negated scalar np merged in the activation:
    // exp2(-tot) = exp2(np - raw). MFMA C-in is a persistent zero vector.
    i32x8 bfr[4];
    #pragma unroll
    for (int q = 0; q < 4; ++q) {
        const int uu = w * 16 + q * 4 + usub;   // unit of this lane's col in MFMA q
        const bool uv = (uu < HID);
        const int r  = gate * HID + (uv ? uu : 0);
        const float Lg = is_g ? (2.0f * LOG2E) : LOG2E;
        i32x8 f;
        #pragma unroll
        for (int d = 0; d < 8; ++d) {
            const int k0 = l16 * 32 + d * 4;
            float v0 = 0.f, v1 = 0.f, v2 = 0.f, v3 = 0.f;
            if (uv) {
                if (k0     < HID) v0 = Lg * W_hh[r * HID + k0];
                if (k0 + 1 < HID) v1 = Lg * W_hh[r * HID + k0 + 1];
                if (k0 + 2 < HID) v2 = Lg * W_hh[r * HID + k0 + 2];
                if (k0 + 3 < HID) v3 = Lg * W_hh[r * HID + k0 + 3];
            }
            int reg = __builtin_amdgcn_cvt_pk_fp8_f32(v0, v1, 0,   false);
            reg     = __builtin_amdgcn_cvt_pk_fp8_f32(v2, v3, reg, true);
            f[d] = reg;
        }
        bfr[q] = f;
    }
    // own (gate, unit) bias/input coefficients (negated, pre-scaled)
    const int rown = gate * HID + (uvalid ? unit : 0);
    const float Lgo = is_g ? (2.0f * LOG2E) : LOG2E;
    const float nwi = uvalid ? -Lgo * W_ih[rown] : 0.0f;
    const float nbs = uvalid ? -Lgo * (b_ih[rown] + b_hh[rown]) : 0.0f;

    float c = 0.0f;
    float h = 0.0f;
    const int aoff = l16 * 32;
    const f32x4 czero = {0.f, 0.f, 0.f, 0.f};
    const bool lb0 = (l16 & 1) != 0;
    const bool lb1 = (l16 & 2) != 0;
    __syncthreads();

    // One LSTM step: read fp8 h from hb, write new fp8 h to hn.
    auto step = [&](const unsigned char* hb, unsigned char* hn, const float xt) {
        const float np = fmaf(nwi, xt, nbs);   // off the LDS critical path

        // A = h broadcast to all 16 rows: one 32-B broadcast read per lane.
        const i32x8 av = *(const i32x8*)(hb + aoff);

        // 4 MFMAs, K=128 each, C-in = zero (scales = 1.0: e8m0 0x7F)
        const f32x4 a0 = __builtin_amdgcn_mfma_scale_f32_16x16x128_f8f6f4(
                 av, bfr[0], czero, 0, 0, 0, 0x7F7F7F7F, 0, 0x7F7F7F7F);
        const f32x4 a1 = __builtin_amdgcn_mfma_scale_f32_16x16x128_f8f6f4(
                 av, bfr[1], czero, 0, 0, 0, 0x7F7F7F7F, 0, 0x7F7F7F7F);
        const f32x4 a2 = __builtin_amdgcn_mfma_scale_f32_16x16x128_f8f6f4(
                 av, bfr[2], czero, 0, 0, 0, 0x7F7F7F7F, 0, 0x7F7F7F7F);
        const f32x4 a3 = __builtin_amdgcn_mfma_scale_f32_16x16x128_f8f6f4(
                 av, bfr[3], czero, 0, 0, 0, 0x7F7F7F7F, 0, 0x7F7F7F7F);

        // this lane's raw = column-group q == l16 (3 cndmasks; rows identical
        // so reg 0 is fine)
        const float t0  = lb0 ? a1[0] : a0[0];
        const float t1  = lb0 ? a3[0] : a2[0];
        const float raw = lb1 ? t1 : t0;

        // ONE activation per lane (own gate): sigmoid, or tanh for g~
        const float e   = __builtin_amdgcn_exp2f(np - raw);
        const float r   = __builtin_amdgcn_rcpf(1.0f + e);
        const float act = is_g ? fmaf(2.0f, r, -1.0f) : r;

        // quad DPP broadcast: lanes 0..3 of the quad hold i,f,g~,o of ONE unit
        const float ig = dpp_mov<0x00>(act);
        const float fg = dpp_mov<0x55>(act);
        const float gg = dpp_mov<0xAA>(act);
        const float og = dpp_mov<0xFF>(act);

        c = fmaf(fg, c, ig * gg);
        const float th = fmaf(2.0f, __builtin_amdgcn_rcpf(
                              1.0f + __builtin_amdgcn_exp2f(-2.0f * LOG2E * c)), -1.0f);
        h = og * th;

        if (writer) {
            const int pk = __builtin_amdgcn_cvt_pk_fp8_f32(h, 0.0f, 0, false);
            hn[unit] = (unsigned char)(pk & 0xFF);
        }
        __syncthreads();
    };

    for (int t = 0; t < T_STEPS; t += 2) {
        step(hbuf[0], hbuf[1], x_lds[t]);
        step(hbuf[1], hbuf[0], x_lds[t + 1]);
    }

    // final h (f32, full precision) for the head — written once
    if (writer) hfin[unit] = h;
    if (tid >= HID && tid < KP) hfin[tid] = 0.0f;
    __syncthreads();

    // head: lin = W1 @ h + b1 (64), out = W2 @ lin + b2 (scalar) — f32 h
    if (tid < 64) {
        const float* rw = W1 + tid * HID;
        float a = 0.0f;
        for (int k = 0; k < HID; ++k)
            a = fmaf(rw[k], hfin[k], a);
        red_lds[tid] = a + b1[tid];
    }
    __syncthreads();
    if (tid == 0) {
        float a = b2[0];
        for (int k = 0; k < 64; ++k)
            a = fmaf(W2[k], red_lds[k], a);
        out[0] = a;
    }
}

extern "C" void kernel_launch(void* const* d_in, const int* in_sizes, int n_in,
                              void* d_out, int out_size, void* d_ws, size_t ws_size,
                              hipStream_t stream) {
    lstm_caviar_kernel<<<1, NTH, 0, stream>>>(
        (const float*)d_in[0],  // input_seq
        (const float*)d_in[1],  // W_ih
        (const float*)d_in[2],  // W_hh
        (const float*)d_in[3],  // b_ih
        (const float*)d_in[4],  // b_hh
        (const float*)d_in[5],  // W1
        (const float*)d_in[6],  // b1
        (const float*)d_in[7],  // W2
        (const float*)d_in[8],  // b2
        (float*)d_out);
}

// Round 15
// 623.606 us; speedup vs baseline: 2.3077x; 1.0783x over previous
//
#include <hip/hip_runtime.h>
#include <hip/hip_fp16.h>

#define T_STEPS 2048
#define BATCH   128
#define HID     100     // LSTM hidden size
#define KP      128     // padded K: [0..99]=h (fp8), 100..127 = 0
#define NTH     448     // 7 waves; MFMA counts 4,4,4,4,3,3,3 -> exactly 100 units

#define LOG2E 1.44269504088896340736f

typedef int   i32x8 __attribute__((ext_vector_type(8)));
typedef float f32x4 __attribute__((ext_vector_type(4)));

// DPP quad_perm helpers (VALU pipe, immediate ctrl)
template <int CTRL>
__device__ __forceinline__ float dpp_mov(float v) {
    int y = __builtin_amdgcn_update_dpp(0, __float_as_int(v), CTRL, 0xF, 0xF, true);
    return __int_as_float(y);
}

__global__ __launch_bounds__(NTH)
void lstm_caviar_kernel(
    const float* __restrict__ x,      // [T, B, 1]
    const float* __restrict__ W_ih,   // [400, 1]
    const float* __restrict__ W_hh,   // [400, 100]
    const float* __restrict__ b_ih,   // [400]
    const float* __restrict__ b_hh,   // [400]
    const float* __restrict__ W1,     // [64, 100]
    const float* __restrict__ b1,     // [64]
    const float* __restrict__ W2,     // [1, 64]
    const float* __restrict__ b2,     // [1]
    float* __restrict__ out)          // [1]
{
    // h as fp8 e4m3 (double-buffered, 128 B each): one barrier per step.
    __shared__ __align__(32) unsigned char hbuf[2][KP];
    __shared__ float hfin[KP];        // f32 h (written once, after the loop)
    __shared__ float x_lds[T_STEPS];
    __shared__ float red_lds[64];

    const int tid  = threadIdx.x;
    const int w    = tid >> 6;        // wave id 0..6
    const int n    = tid & 15;        // MFMA col (C/D: col = lane&15, m89)
    const int gate = n & 3;           // this lane's gate (0=i,1=f,2=g~,3=o)
    const int usub = n >> 2;          // unit-sub within a 4-unit column group
    const int l16  = (tid >> 4) & 3;  // k-group for fragments AND col-group q

    // Unequal MFMA distribution (zero column padding): waves 0-3 issue 4
    // MFMAs (16 units each: 0..63), waves 4-6 issue 3 (12 units each:
    // 64..99). Busiest SIMD: 4+3 = 7 MFMAs/step (was 8 with padding).
    const bool w4     = (w < 4);
    const int  base   = w4 ? (16 * w) : (64 + 12 * (w - 4));
    const bool qvalid = w4 || (l16 < 3);        // lane has a (gate,unit) pair?
    const int  unit   = base + 4 * l16 + usub;  // valid iff qvalid (<100 then)
    const bool writer = (gate == 0) && qvalid;
    const bool is_g   = (gate == 2);

    // stage batch-0 inputs (x[t,0,0] = flat[t*BATCH]) into LDS once
    for (int t = tid; t < T_STEPS; t += NTH)
        x_lds[t] = x[t * BATCH];
    if (tid < KP) { hbuf[0][tid] = 0; hbuf[1][tid] = 0; }

    // Static B fragments (fp8 e4m3), one per column-group q. Lane's 32 bytes
    // cover k = l16*32 + d*4 + byte — SAME k-labeling as A, so any mismatch vs
    // the true HW k-mapping cancels in the K-contraction (HW-validated R10+).
    // Rows pre-scaled by log2e (2x for gate g~) so activations use raw exp2.
    // Bias + W_ih*x enter as a negated scalar np merged in the activation:
    // exp2(-tot) = exp2(np - raw). MFMA C-in is a persistent zero vector.
    i32x8 bfr[4];
    #pragma unroll
    for (int q = 0; q < 4; ++q) {
        const int uu = base + 4 * q + usub;     // unit of this lane's col in MFMA q
        const bool uv = (uu < HID);
        const int r  = gate * HID + (uv ? uu : 0);
        const float Lg = is_g ? (2.0f * LOG2E) : LOG2E;
        i32x8 f;
        #pragma unroll
        for (int d = 0; d < 8; ++d) {
            const int k0 = l16 * 32 + d * 4;
            float v0 = 0.f, v1 = 0.f, v2 = 0.f, v3 = 0.f;
            if (uv) {
                if (k0     < HID) v0 = Lg * W_hh[r * HID + k0];
                if (k0 + 1 < HID) v1 = Lg * W_hh[r * HID + k0 + 1];
                if (k0 + 2 < HID) v2 = Lg * W_hh[r * HID + k0 + 2];
                if (k0 + 3 < HID) v3 = Lg * W_hh[r * HID + k0 + 3];
            }
            int reg = __builtin_amdgcn_cvt_pk_fp8_f32(v0, v1, 0,   false);
            reg     = __builtin_amdgcn_cvt_pk_fp8_f32(v2, v3, reg, true);
            f[d] = reg;
        }
        bfr[q] = f;
    }
    // own (gate, unit) bias/input coefficients (negated, pre-scaled)
    const int rown = gate * HID + (qvalid ? unit : 0);
    const float Lgo = is_g ? (2.0f * LOG2E) : LOG2E;
    const float nwi = qvalid ? -Lgo * W_ih[rown] : 0.0f;
    const float nbs = qvalid ? -Lgo * (b_ih[rown] + b_hh[rown]) : 0.0f;

    float c = 0.0f;
    float h = 0.0f;
    const int aoff = l16 * 32;
    const f32x4 czero = {0.f, 0.f, 0.f, 0.f};
    const bool lb0 = (l16 & 1) != 0;
    const bool lb1 = (l16 & 2) != 0;
    __syncthreads();

    // One LSTM step: read fp8 h from hb, write new fp8 h to hn.
    auto step = [&](const unsigned char* hb, unsigned char* hn, const float xt) {
        const float np = fmaf(nwi, xt, nbs);   // off the LDS critical path

        // A = h broadcast to all 16 rows: one 32-B broadcast read per lane.
        const i32x8 av = *(const i32x8*)(hb + aoff);

        // 3 or 4 MFMAs, K=128 each, C-in = zero (scales = 1.0: e8m0 0x7F)
        const f32x4 a0 = __builtin_amdgcn_mfma_scale_f32_16x16x128_f8f6f4(
                 av, bfr[0], czero, 0, 0, 0, 0x7F7F7F7F, 0, 0x7F7F7F7F);
        const f32x4 a1 = __builtin_amdgcn_mfma_scale_f32_16x16x128_f8f6f4(
                 av, bfr[1], czero, 0, 0, 0, 0x7F7F7F7F, 0, 0x7F7F7F7F);
        const f32x4 a2 = __builtin_amdgcn_mfma_scale_f32_16x16x128_f8f6f4(
                 av, bfr[2], czero, 0, 0, 0, 0x7F7F7F7F, 0, 0x7F7F7F7F);
        f32x4 a3 = czero;
        if (w4)                            // wave-uniform branch
            a3 = __builtin_amdgcn_mfma_scale_f32_16x16x128_f8f6f4(
                 av, bfr[3], czero, 0, 0, 0, 0x7F7F7F7F, 0, 0x7F7F7F7F);

        // this lane's raw = column-group q == l16 (3 cndmasks; rows identical
        // so reg 0 is fine)
        const float t0  = lb0 ? a1[0] : a0[0];
        const float t1  = lb0 ? a3[0] : a2[0];
        const float raw = lb1 ? t1 : t0;

        // ONE activation per lane (own gate): sigmoid, or tanh for g~
        const float e   = __builtin_amdgcn_exp2f(np - raw);
        const float r   = __builtin_amdgcn_rcpf(1.0f + e);
        const float act = is_g ? fmaf(2.0f, r, -1.0f) : r;

        // 2-DPP c-update: prod(lane0) = i*g via one quad-swap product; c is
        // valid in gate-0 (and gate-2) lanes only — writer is gate 0.
        const float prod = act * dpp_mov<0x4E>(act);   // lane0: act0*act2 = i*g
        const float fg   = dpp_mov<0x55>(act);         // f broadcast
        c = fmaf(fg, c, prod);
        const float th = fmaf(2.0f, __builtin_amdgcn_rcpf(
                              1.0f + __builtin_amdgcn_exp2f(-2.0f * LOG2E * c)), -1.0f);
        const float og = dpp_mov<0xFF>(act);           // o broadcast
        h = og * th;

        if (writer) {
            const int pk = __builtin_amdgcn_cvt_pk_fp8_f32(h, 0.0f, 0, false);
            hn[unit] = (unsigned char)(pk & 0xFF);
        }
        __syncthreads();
    };

    for (int t = 0; t < T_STEPS; t += 2) {
        step(hbuf[0], hbuf[1], x_lds[t]);
        step(hbuf[1], hbuf[0], x_lds[t + 1]);
    }

    // final h (f32, full precision) for the head — written once
    if (writer) hfin[unit] = h;
    if (tid >= HID && tid < KP) hfin[tid] = 0.0f;
    __syncthreads();

    // head: lin = W1 @ h + b1 (64), out = W2 @ lin + b2 (scalar) — f32 h
    if (tid < 64) {
        const float* rw = W1 + tid * HID;
        float a = 0.0f;
        for (int k = 0; k < HID; ++k)
            a = fmaf(rw[k], hfin[k], a);
        red_lds[tid] = a + b1[tid];
    }
    __syncthreads();
    if (tid == 0) {
        float a = b2[0];
        for (int k = 0; k < 64; ++k)
            a = fmaf(W2[k], red_lds[k], a);
        out[0] = a;
    }
}

extern "C" void kernel_launch(void* const* d_in, const int* in_sizes, int n_in,
                              void* d_out, int out_size, void* d_ws, size_t ws_size,
                              hipStream_t stream) {
    lstm_caviar_kernel<<<1, NTH, 0, stream>>>(
        (const float*)d_in[0],  // input_seq
        (const float*)d_in[1],  // W_ih
        (const float*)d_in[2],  // W_hh
        (const float*)d_in[3],  // b_ih
        (const float*)d_in[4],  // b_hh
        (const float*)d_in[5],  // W1
        (const float*)d_in[6],  // b1
        (const float*)d_in[7],  // W2
        (const float*)d_in[8],  // b2
        (float*)d_out);
}

// Round 16
// 619.197 us; speedup vs baseline: 2.3241x; 1.0071x over previous
//
#include <hip/hip_runtime.h>
#include <hip/hip_fp16.h>

#define T_STEPS 2048
#define BATCH   128
#define HID     100     // LSTM hidden size
#define KP      128     // padded K: [0..99]=h (fp8), 100..127 = 0
#define NTH     448     // 7 waves; MFMA counts 4,4,4,4,3,3,3 -> exactly 100 units

#define LOG2E 1.44269504088896340736f

typedef int   i32x8 __attribute__((ext_vector_type(8)));
typedef float f32x4 __attribute__((ext_vector_type(4)));

// DPP quad_perm helpers (VALU pipe, immediate ctrl)
template <int CTRL>
__device__ __forceinline__ float dpp_mov(float v) {
    int y = __builtin_amdgcn_update_dpp(0, __float_as_int(v), CTRL, 0xF, 0xF, true);
    return __int_as_float(y);
}

__global__ __launch_bounds__(NTH)
void lstm_caviar_kernel(
    const float* __restrict__ x,      // [T, B, 1]
    const float* __restrict__ W_ih,   // [400, 1]
    const float* __restrict__ W_hh,   // [400, 100]
    const float* __restrict__ b_ih,   // [400]
    const float* __restrict__ b_hh,   // [400]
    const float* __restrict__ W1,     // [64, 100]
    const float* __restrict__ b1,     // [64]
    const float* __restrict__ W2,     // [1, 64]
    const float* __restrict__ b2,     // [1]
    float* __restrict__ out)          // [1]
{
    // h as fp8 e4m3 (double-buffered, 128 B each): one barrier per step.
    __shared__ __align__(32) unsigned char hbuf[2][KP];
    __shared__ float hfin[KP];        // f32 h (written once, after the loop)
    __shared__ __align__(8) float x_lds[T_STEPS];
    __shared__ float red_lds[64];

    const int tid  = threadIdx.x;
    const int w    = tid >> 6;        // wave id 0..6
    const int n    = tid & 15;        // MFMA col (C/D: col = lane&15, m89)
    const int gate = n & 3;           // this lane's gate (0=i,1=f,2=g~,3=o)
    const int usub = n >> 2;          // unit-sub within a 4-unit column group
    const int l16  = (tid >> 4) & 3;  // k-group for fragments AND col-group q

    // Unequal MFMA distribution (zero column padding): waves 0-3 issue 4
    // MFMAs (16 units each: 0..63), waves 4-6 issue 3 (12 units each:
    // 64..99). Busiest SIMD: 4+3 = 7 MFMAs/step — the provable floor
    // (25 MFMAs minimal for 400 outputs at 16 cols/MFMA; ceil(25/4)=7).
    const bool w4     = (w < 4);
    const int  base   = w4 ? (16 * w) : (64 + 12 * (w - 4));
    const bool qvalid = w4 || (l16 < 3);        // lane has a (gate,unit) pair?
    const int  unit   = base + 4 * l16 + usub;  // valid iff qvalid (<100 then)
    const bool writer = (gate == 0) && qvalid;
    const bool is_g   = (gate == 2);

    // stage batch-0 inputs (x[t,0,0] = flat[t*BATCH]) into LDS once
    for (int t = tid; t < T_STEPS; t += NTH)
        x_lds[t] = x[t * BATCH];
    if (tid < KP) { hbuf[0][tid] = 0; hbuf[1][tid] = 0; }

    // Static B fragments (fp8 e4m3), one per column-group q. Lane's 32 bytes
    // cover k = l16*32 + d*4 + byte — SAME k-labeling as A, so any mismatch vs
    // the true HW k-mapping cancels in the K-contraction (HW-validated R10+).
    // Rows pre-scaled by log2e (2x for gate g~) so activations use raw exp2.
    // Bias + W_ih*x enter as a negated scalar np merged in the activation:
    // exp2(-tot) = exp2(np - raw). MFMA C-in is a persistent zero vector.
    i32x8 bfr[4];
    #pragma unroll
    for (int q = 0; q < 4; ++q) {
        const int uu = base + 4 * q + usub;     // unit of this lane's col in MFMA q
        const bool uv = (uu < HID);
        const int r  = gate * HID + (uv ? uu : 0);
        const float Lg = is_g ? (2.0f * LOG2E) : LOG2E;
        i32x8 f;
        #pragma unroll
        for (int d = 0; d < 8; ++d) {
            const int k0 = l16 * 32 + d * 4;
            float v0 = 0.f, v1 = 0.f, v2 = 0.f, v3 = 0.f;
            if (uv) {
                if (k0     < HID) v0 = Lg * W_hh[r * HID + k0];
                if (k0 + 1 < HID) v1 = Lg * W_hh[r * HID + k0 + 1];
                if (k0 + 2 < HID) v2 = Lg * W_hh[r * HID + k0 + 2];
                if (k0 + 3 < HID) v3 = Lg * W_hh[r * HID + k0 + 3];
            }
            int reg = __builtin_amdgcn_cvt_pk_fp8_f32(v0, v1, 0,   false);
            reg     = __builtin_amdgcn_cvt_pk_fp8_f32(v2, v3, reg, true);
            f[d] = reg;
        }
        bfr[q] = f;
    }
    // own (gate, unit) bias/input coefficients (negated, pre-scaled)
    const int rown = gate * HID + (qvalid ? unit : 0);
    const float Lgo = is_g ? (2.0f * LOG2E) : LOG2E;
    const float nwi = qvalid ? -Lgo * W_ih[rown] : 0.0f;
    const float nbs = qvalid ? -Lgo * (b_ih[rown] + b_hh[rown]) : 0.0f;

    float c = 0.0f;
    float h = 0.0f;
    // hoisted per-lane addresses: substep entry is a pure ds_read
    const unsigned char* pA = hbuf[0] + l16 * 32;
    const unsigned char* pB = hbuf[1] + l16 * 32;
    unsigned char* wA = hbuf[0] + (qvalid ? unit : 0);
    unsigned char* wB = hbuf[1] + (qvalid ? unit : 0);
    const f32x4 czero = {0.f, 0.f, 0.f, 0.f};
    const bool lb0 = (l16 & 1) != 0;
    const bool lb1 = (l16 & 2) != 0;
    __syncthreads();

    // One LSTM step: read fp8 h via pr, write new fp8 h via pw.
    // np precomputed at iteration top (off the critical entry path).
    auto step = [&](const unsigned char* pr, unsigned char* pw, const float np) {
        // A = h broadcast to all 16 rows: one 32-B broadcast read per lane.
        const i32x8 av = *(const i32x8*)pr;

        // 3 or 4 MFMAs, K=128 each, C-in = zero (scales = 1.0: e8m0 0x7F)
        const f32x4 a0 = __builtin_amdgcn_mfma_scale_f32_16x16x128_f8f6f4(
                 av, bfr[0], czero, 0, 0, 0, 0x7F7F7F7F, 0, 0x7F7F7F7F);
        const f32x4 a1 = __builtin_amdgcn_mfma_scale_f32_16x16x128_f8f6f4(
                 av, bfr[1], czero, 0, 0, 0, 0x7F7F7F7F, 0, 0x7F7F7F7F);
        const f32x4 a2 = __builtin_amdgcn_mfma_scale_f32_16x16x128_f8f6f4(
                 av, bfr[2], czero, 0, 0, 0, 0x7F7F7F7F, 0, 0x7F7F7F7F);
        f32x4 a3 = czero;
        if (w4)                            // wave-uniform branch
            a3 = __builtin_amdgcn_mfma_scale_f32_16x16x128_f8f6f4(
                 av, bfr[3], czero, 0, 0, 0, 0x7F7F7F7F, 0, 0x7F7F7F7F);

        // this lane's raw = column-group q == l16 (rows identical -> reg 0)
        const float t0  = lb0 ? a1[0] : a0[0];
        const float t1  = lb0 ? a3[0] : a2[0];
        const float raw = lb1 ? t1 : t0;

        // ONE activation per lane (own gate): sigmoid, or tanh for g~
        const float e   = __builtin_amdgcn_exp2f(np - raw);
        const float r   = __builtin_amdgcn_rcpf(1.0f + e);
        const float act = is_g ? fmaf(2.0f, r, -1.0f) : r;

        // 2-DPP c-update: lane0's quad-swap product = i*g; writer is gate 0.
        const float prod = act * dpp_mov<0x4E>(act);
        const float fg   = dpp_mov<0x55>(act);
        c = fmaf(fg, c, prod);
        const float th = fmaf(2.0f, __builtin_amdgcn_rcpf(
                              1.0f + __builtin_amdgcn_exp2f(-2.0f * LOG2E * c)), -1.0f);
        const float og = dpp_mov<0xFF>(act);
        h = og * th;

        if (writer) {
            const int pk = __builtin_amdgcn_cvt_pk_fp8_f32(h, 0.0f, 0, false);
            *pw = (unsigned char)pk;       // ds_write_b8 takes low 8 bits
        }
        __syncthreads();
    };

    for (int t = 0; t < T_STEPS; t += 2) {
        // both substeps' x + bias terms computed up front, off the chain
        const float2 xp = *(const float2*)(x_lds + t);
        const float npA = fmaf(nwi, xp.x, nbs);
        const float npB = fmaf(nwi, xp.y, nbs);
        step(pA, wB, npA);
        step(pB, wA, npB);
    }

    // final h (f32, full precision) for the head — written once
    if (writer) hfin[unit] = h;
    if (tid >= HID && tid < KP) hfin[tid] = 0.0f;
    __syncthreads();

    // head: lin = W1 @ h + b1 (64), out = W2 @ lin + b2 (scalar) — f32 h
    if (tid < 64) {
        const float* rw = W1 + tid * HID;
        float a = 0.0f;
        for (int k = 0; k < HID; ++k)
            a = fmaf(rw[k], hfin[k], a);
        red_lds[tid] = a + b1[tid];
    }
    __syncthreads();
    if (tid == 0) {
        float a = b2[0];
        for (int k = 0; k < 64; ++k)
            a = fmaf(W2[k], red_lds[k], a);
        out[0] = a;
    }
}

extern "C" void kernel_launch(void* const* d_in, const int* in_sizes, int n_in,
                              void* d_out, int out_size, void* d_ws, size_t ws_size,
                              hipStream_t stream) {
    lstm_caviar_kernel<<<1, NTH, 0, stream>>>(
        (const float*)d_in[0],  // input_seq
        (const float*)d_in[1],  // W_ih
        (const float*)d_in[2],  // W_hh
        (const float*)d_in[3],  // b_ih
        (const float*)d_in[4],  // b_hh
        (const float*)d_in[5],  // W1
        (const float*)d_in[6],  // b1
        (const float*)d_in[7],  // W2
        (const float*)d_in[8],  // b2
        (float*)d_out);
}